// Round 4
// baseline (13026.865 us; speedup 1.0000x reference)
//
#include <hip/hip_runtime.h>
#include <hip/hip_fp16.h>
#include <stdint.h>

// HamiltonianFlow: x [256, 8, 32, 2] (q,p); H = 0.5*sum(p^2) + MLP(q).
// dq/dt = p, dp/dt = -W1 @ [(1-tanh(z)^2) * W2], z = q^T W1 + b1.
// 100 RK4 steps = 400 strictly sequential fwd+bwd MLP evals.
//
// R4: one block / batch element (256 blocks, 1/CU), 512 threads (8 waves,
// 2/SIMD -> 256 unified regs/thread so the 128 weight VGPRs stay ARCH VGPRs;
// R3's 1024-thread config forced 4 waves/SIMD -> weights spilled to AGPRs ->
// v_accvgpr_read before every fma_mix = 2x VALU issue, VGPR_Count=52 proved it).
// Wave w owns components [32w,32w+32): lane (c=l>>5, sub=l&31) sums half the
// inner dim; one __shfl_xor(32) finishes the dot product -> only 2 barriers
// per eval (R3 had 4) and nonlinearity/RK4 bookkeeping run on ALL waves.
// Numerics unchanged from R3 (passed at 1.95e-3): f16 packed storage,
// v_fma_mix_f32 = exact f32 FMA on f16-converted operands.

#define NSTEPS 100

__device__ __forceinline__ uint16_t h16(float x) {
    return __half_as_ushort(__float2half_rn(x));
}
__device__ __forceinline__ uint32_t packh2(float a, float b) {
    return (uint32_t)h16(a) | ((uint32_t)h16(b) << 16);
}

// acc += f32(f16 half of w) * f32(f16 half of x)  -- exact fp32 fma
#define FMAMIX_LL(acc, w, x) \
    asm("v_fma_mix_f32 %0, %1, %2, %0 op_sel:[0,0,0] op_sel_hi:[1,1,0]" \
        : "+v"(acc) : "v"(w), "v"(x))
#define FMAMIX_HH(acc, w, x) \
    asm("v_fma_mix_f32 %0, %1, %2, %0 op_sel:[1,1,0] op_sel_hi:[1,1,0]" \
        : "+v"(acc) : "v"(w), "v"(x))

__global__ __launch_bounds__(512, 2)
void ham_kernel(const float* __restrict__ x0, const float* __restrict__ W1,
                const float* __restrict__ b1, const float* __restrict__ W2,
                float* __restrict__ out)
{
    __shared__ __align__(16) uint16_t qsh[256];  // q broadcast, packed f16
    __shared__ __align__(16) uint16_t ush[256];  // u broadcast, packed f16

    const int t = threadIdx.x;
    const int l = t & 63;
    const int sub = l & 31;              // element within wave's 32-group
    const int c = l >> 5;                // inner-dim half: [128c, 128c+128)
    const int idx = (t >> 6) * 32 + sub; // owned j (fwd) / i (bwd) / state comp
    const int blk = blockIdx.x;

    // ---- W1 -> arch VGPRs, packed f16, both orientations ----
    // wcol[k] = (W[128c+2k][idx],  W[128c+2k+1][idx])   forward column
    // wrow[k] = (W[idx][128c+2k],  W[idx][128c+2k+1])   backward row
    uint32_t wcol[64], wrow[64];
    {
        const float* Wc = W1 + (128 * c) * 256 + idx;
        #pragma unroll 8
        for (int k = 0; k < 64; ++k)
            wcol[k] = packh2(Wc[(2 * k) * 256], Wc[(2 * k + 1) * 256]);
        const float* Wr = W1 + idx * 256 + 128 * c;
        #pragma unroll 8
        for (int k = 0; k < 32; ++k) {
            float4 v = *(const float4*)(Wr + 4 * k);
            wrow[2 * k]     = packh2(v.x, v.y);
            wrow[2 * k + 1] = packh2(v.z, v.w);
        }
    }
    const float b1r = b1[idx];
    const float w2r = W2[idx];

    // state for component idx, replicated across the two c-halves
    float2 qp = ((const float2*)(x0 + (size_t)blk * 512))[idx];
    float q0 = qp.x, p0 = qp.y;
    if (c == 0) qsh[idx] = h16(q0);
    __syncthreads();

    const float dt = 0.01f;
    float accq = 0.f, accp = 0.f, qs = q0, ps = p0;

    #pragma unroll 1
    for (int it = 0; it < NSTEPS * 4; ++it) {
        const int s = it & 3;

        // ---- forward: z_idx = sum_i q_i W[i][idx]; lane sums i in [128c,+128)
        float a0 = 0.f, a1 = 0.f;
        {
            const uint4* qv4 = (const uint4*)(qsh + 128 * c);
            #pragma unroll
            for (int kk = 0; kk < 16; ++kk) {
                uint4 qv = qv4[kk];
                FMAMIX_LL(a0, wcol[4 * kk + 0], qv.x);
                FMAMIX_HH(a1, wcol[4 * kk + 0], qv.x);
                FMAMIX_LL(a0, wcol[4 * kk + 1], qv.y);
                FMAMIX_HH(a1, wcol[4 * kk + 1], qv.y);
                FMAMIX_LL(a0, wcol[4 * kk + 2], qv.z);
                FMAMIX_HH(a1, wcol[4 * kk + 2], qv.z);
                FMAMIX_LL(a0, wcol[4 * kk + 3], qv.w);
                FMAMIX_HH(a1, wcol[4 * kk + 3], qv.w);
            }
        }
        float zpart = a0 + a1;
        float z = zpart + __shfl_xor(zpart, 32, 64) + b1r;

        // ---- nonlinearity (all waves, own 32 j's; replicated over c)
        float e = __expf(2.f * z);          // tanh via exp; saturates ok
        float hh = 1.f - 2.f / (e + 1.f);
        float u = (1.f - hh * hh) * w2r;
        if (c == 0) ush[idx] = h16(u);
        __syncthreads();

        // ---- backward: g_idx = sum_j W[idx][j] u_j; lane sums j in [128c,+128)
        float g0 = 0.f, g1 = 0.f;
        {
            const uint4* uv4 = (const uint4*)(ush + 128 * c);
            #pragma unroll
            for (int kk = 0; kk < 16; ++kk) {
                uint4 uv = uv4[kk];
                FMAMIX_LL(g0, wrow[4 * kk + 0], uv.x);
                FMAMIX_HH(g1, wrow[4 * kk + 0], uv.x);
                FMAMIX_LL(g0, wrow[4 * kk + 1], uv.y);
                FMAMIX_HH(g1, wrow[4 * kk + 1], uv.y);
                FMAMIX_LL(g0, wrow[4 * kk + 2], uv.z);
                FMAMIX_HH(g1, wrow[4 * kk + 2], uv.z);
                FMAMIX_LL(g0, wrow[4 * kk + 3], uv.w);
                FMAMIX_HH(g1, wrow[4 * kk + 3], uv.w);
            }
        }
        float gpart = g0 + g1;
        float g = gpart + __shfl_xor(gpart, 32, 64);

        // ---- RK4 bookkeeping (all waves; identical across c-halves)
        float kq = ps, kp = -g;
        float wgt = (s == 0 || s == 3) ? 1.f : 2.f;
        accq += wgt * kq;
        accp += wgt * kp;
        float qn;
        if (s < 3) {
            float a = (s == 2) ? dt : 0.5f * dt;
            qs = q0 + a * kq;
            ps = p0 + a * kp;
            qn = qs;
        } else {
            q0 += (dt / 6.f) * accq;
            p0 += (dt / 6.f) * accp;
            accq = 0.f; accp = 0.f;
            qs = q0; ps = p0;
            qn = q0;
        }
        if (c == 0) qsh[idx] = h16(qn);
        __syncthreads();
    }

    if (c == 0)
        ((float2*)(out + (size_t)blk * 512))[idx] = make_float2(q0, p0);
}

extern "C" void kernel_launch(void* const* d_in, const int* in_sizes, int n_in,
                              void* d_out, int out_size, void* d_ws, size_t ws_size,
                              hipStream_t stream) {
    const float* x0 = (const float*)d_in[0];
    const float* W1 = (const float*)d_in[1];
    const float* b1 = (const float*)d_in[2];
    const float* W2 = (const float*)d_in[3];
    // d_in[4] = b2: constant offset, no effect on the gradient/dynamics.
    float* out = (float*)d_out;
    hipLaunchKernelGGL(ham_kernel, dim3(256), dim3(512), 0, stream,
                       x0, W1, b1, W2, out);
}

// Round 5
// 712.142 us; speedup vs baseline: 18.2925x; 18.2925x over previous
//
#include <hip/hip_runtime.h>
#include <hip/hip_fp16.h>
#include <stdint.h>

// HamiltonianFlow: x [256, 8, 32, 2] (q,p); H = 0.5*sum(p^2) + MLP(q).
// dq/dt = p, dp/dt = -W1 @ [(1-tanh(z)^2) * W2], z = q^T W1 + b1.
// 100 RK4 steps = 400 strictly sequential fwd+bwd MLP evals.
//
// R5 = R4 structure with the spill fixed. R4's VGPR_Count=32 + FETCH 13GB
// proved wcol/wrow went to SCRATCH: partial-unroll pragmas left dynamic
// array indices, which blocks register promotion. EVERY loop touching the
// weight arrays below is now fully unrolled (compile-time indices only).
// Check: VGPR_Count must be ~180-240; if it reads ~32, the arrays spilled.
//
// Structure: one block / batch element (256 blocks, 1/CU), 512 threads
// (8 waves, 2/SIMD -> 256-reg budget). Wave w owns components [32w,32w+32);
// lane (c=l>>5, sub=l&31) sums inner-dim half [128c,128c+128); one
// __shfl_xor(32) completes each dot product; 2 barriers/eval.
// Numerics (validated R3: absmax 1.95e-3): f16 packed storage,
// v_fma_mix_f32 = exact fp32 FMA on exactly-converted f16 operands.

#define NSTEPS 100

__device__ __forceinline__ uint16_t h16(float x) {
    return __half_as_ushort(__float2half_rn(x));
}
__device__ __forceinline__ uint32_t packh2(float a, float b) {
    return (uint32_t)h16(a) | ((uint32_t)h16(b) << 16);
}

// acc += f32(f16 half of w) * f32(f16 half of x)  -- exact fp32 fma
#define FMAMIX_LL(acc, w, x) \
    asm("v_fma_mix_f32 %0, %1, %2, %0 op_sel:[0,0,0] op_sel_hi:[1,1,0]" \
        : "+v"(acc) : "v"(w), "v"(x))
#define FMAMIX_HH(acc, w, x) \
    asm("v_fma_mix_f32 %0, %1, %2, %0 op_sel:[1,1,0] op_sel_hi:[1,1,0]" \
        : "+v"(acc) : "v"(w), "v"(x))

__global__ __launch_bounds__(512, 2)
void ham_kernel(const float* __restrict__ x0, const float* __restrict__ W1,
                const float* __restrict__ b1, const float* __restrict__ W2,
                float* __restrict__ out)
{
    __shared__ __align__(16) uint16_t qsh[256];  // q broadcast, packed f16
    __shared__ __align__(16) uint16_t ush[256];  // u broadcast, packed f16

    const int t = threadIdx.x;
    const int l = t & 63;
    const int sub = l & 31;              // element within wave's 32-group
    const int c = l >> 5;                // inner-dim half: [128c, 128c+128)
    const int idx = (t >> 6) * 32 + sub; // owned j (fwd) / i (bwd) / state comp
    const int blk = blockIdx.x;

    // ---- W1 -> arch VGPRs, packed f16, both orientations ----
    // wcol[k] = (W[128c+2k][idx],  W[128c+2k+1][idx])   forward column
    // wrow[k] = (W[idx][128c+2k],  W[idx][128c+2k+1])   backward row
    // FULL unroll on every access: dynamic index => scratch spill (R4).
    uint32_t wcol[64], wrow[64];
    {
        const float* Wc = W1 + (128 * c) * 256 + idx;
        #pragma unroll
        for (int k = 0; k < 64; ++k)
            wcol[k] = packh2(Wc[(2 * k) * 256], Wc[(2 * k + 1) * 256]);
        const float* Wr = W1 + idx * 256 + 128 * c;
        #pragma unroll
        for (int k = 0; k < 32; ++k) {
            float4 v = *(const float4*)(Wr + 4 * k);
            wrow[2 * k]     = packh2(v.x, v.y);
            wrow[2 * k + 1] = packh2(v.z, v.w);
        }
    }
    const float b1r = b1[idx];
    const float w2r = W2[idx];

    // state for component idx, replicated across the two c-halves
    float2 qp = ((const float2*)(x0 + (size_t)blk * 512))[idx];
    float q0 = qp.x, p0 = qp.y;
    if (c == 0) qsh[idx] = h16(q0);
    __syncthreads();

    const float dt = 0.01f;
    float accq = 0.f, accp = 0.f, qs = q0, ps = p0;

    #pragma unroll 1
    for (int it = 0; it < NSTEPS * 4; ++it) {
        const int s = it & 3;

        // ---- forward: z_idx = sum_i q_i W[i][idx]; lane sums i in [128c,+128)
        float a0 = 0.f, a1 = 0.f;
        {
            const uint4* qv4 = (const uint4*)(qsh + 128 * c);
            #pragma unroll
            for (int kk = 0; kk < 16; ++kk) {
                uint4 qv = qv4[kk];
                FMAMIX_LL(a0, wcol[4 * kk + 0], qv.x);
                FMAMIX_HH(a1, wcol[4 * kk + 0], qv.x);
                FMAMIX_LL(a0, wcol[4 * kk + 1], qv.y);
                FMAMIX_HH(a1, wcol[4 * kk + 1], qv.y);
                FMAMIX_LL(a0, wcol[4 * kk + 2], qv.z);
                FMAMIX_HH(a1, wcol[4 * kk + 2], qv.z);
                FMAMIX_LL(a0, wcol[4 * kk + 3], qv.w);
                FMAMIX_HH(a1, wcol[4 * kk + 3], qv.w);
            }
        }
        float zpart = a0 + a1;
        float z = zpart + __shfl_xor(zpart, 32, 64) + b1r;

        // ---- nonlinearity (all waves, own 32 j's; replicated over c)
        float e = __expf(2.f * z);          // tanh via exp; saturates ok
        float hh = 1.f - 2.f / (e + 1.f);
        float u = (1.f - hh * hh) * w2r;
        if (c == 0) ush[idx] = h16(u);
        __syncthreads();

        // ---- backward: g_idx = sum_j W[idx][j] u_j; lane sums j in [128c,+128)
        float g0 = 0.f, g1 = 0.f;
        {
            const uint4* uv4 = (const uint4*)(ush + 128 * c);
            #pragma unroll
            for (int kk = 0; kk < 16; ++kk) {
                uint4 uv = uv4[kk];
                FMAMIX_LL(g0, wrow[4 * kk + 0], uv.x);
                FMAMIX_HH(g1, wrow[4 * kk + 0], uv.x);
                FMAMIX_LL(g0, wrow[4 * kk + 1], uv.y);
                FMAMIX_HH(g1, wrow[4 * kk + 1], uv.y);
                FMAMIX_LL(g0, wrow[4 * kk + 2], uv.z);
                FMAMIX_HH(g1, wrow[4 * kk + 2], uv.z);
                FMAMIX_LL(g0, wrow[4 * kk + 3], uv.w);
                FMAMIX_HH(g1, wrow[4 * kk + 3], uv.w);
            }
        }
        float gpart = g0 + g1;
        float g = gpart + __shfl_xor(gpart, 32, 64);

        // ---- RK4 bookkeeping (all waves; identical across c-halves)
        float kq = ps, kp = -g;
        float wgt = (s == 0 || s == 3) ? 1.f : 2.f;
        accq += wgt * kq;
        accp += wgt * kp;
        float qn;
        if (s < 3) {
            float a = (s == 2) ? dt : 0.5f * dt;
            qs = q0 + a * kq;
            ps = p0 + a * kp;
            qn = qs;
        } else {
            q0 += (dt / 6.f) * accq;
            p0 += (dt / 6.f) * accp;
            accq = 0.f; accp = 0.f;
            qs = q0; ps = p0;
            qn = q0;
        }
        if (c == 0) qsh[idx] = h16(qn);
        __syncthreads();
    }

    if (c == 0)
        ((float2*)(out + (size_t)blk * 512))[idx] = make_float2(q0, p0);
}

extern "C" void kernel_launch(void* const* d_in, const int* in_sizes, int n_in,
                              void* d_out, int out_size, void* d_ws, size_t ws_size,
                              hipStream_t stream) {
    const float* x0 = (const float*)d_in[0];
    const float* W1 = (const float*)d_in[1];
    const float* b1 = (const float*)d_in[2];
    const float* W2 = (const float*)d_in[3];
    // d_in[4] = b2: constant offset, no effect on the gradient/dynamics.
    float* out = (float*)d_out;
    hipLaunchKernelGGL(ham_kernel, dim3(256), dim3(512), 0, stream,
                       x0, W1, b1, W2, out);
}

// Round 7
// 554.640 us; speedup vs baseline: 23.4870x; 1.2840x over previous
//
#include <hip/hip_runtime.h>
#include <stdint.h>

// HamiltonianFlow: x [256, 8, 32, 2] (q,p); H = 0.5*sum(p^2) + MLP(q).
// dq/dt = p, dp/dt = -W1 @ [(1-tanh(z)^2) * W2], z = q^T W1 + b1.
// 100 RK4 steps = 400 strictly sequential fwd+bwd 256x256 matvecs.
//
// R7 = R6 with the backward-orientation bug fixed. R6 computed W^T u (my
// "g^T = u^T W" identity was wrong algebra; correct is g^T = u^T W^T).
// Both weight orientations are now held in registers (256 VGPRs; gfx950
// MFMA reads A/B from AGPRs too, so unified-file placement is free).
//
// mfma_f32_16x16x32_f16 layouts (m89/m91/m120-verified):
//   A[m=lane&15][k=quad*8+j]; B[k=quad*8+j][n=lane&15];
//   D[row=quad*4+r][col=lane&15],  quad=lane>>4.
// Forward : A = q replicated over rows, B = wA (W[k][n] frag)
//           -> D[.][n]=z[16T+n]: z is LANE-OWNED (tile tt==quad), no bounce.
// Backward: A = wB (W[m][k] frag, contiguous b128 gather), B = u replicated
//           -> D[m][.]=g[16T+m]: s==0 lanes bounce 16B via wave-local LDS.
// One block/batch element (256 blocks, 1/CU), 256 threads (4 waves, 1/SIMD).
// 2 barriers/eval. FULL unroll on every reg-array access (R4: dynamic index
// => scratch). Numerics: f16 storage, fp32 MFMA accumulate (R3/R5 class).

typedef _Float16 v8h __attribute__((ext_vector_type(8)));
typedef _Float16 v4h __attribute__((ext_vector_type(4)));
typedef float v4f __attribute__((ext_vector_type(4)));

#define NSTEPS 100
#define WS 264   // padded f16 row stride (528 B, 16B-aligned, bank shift 4)

__global__ __launch_bounds__(256, 1)
void ham_kernel(const float* __restrict__ x0, const float* __restrict__ W1,
                const float* __restrict__ b1, const float* __restrict__ W2,
                float* __restrict__ out)
{
    __shared__ __align__(16) _Float16 wlds[256 * WS];   // 135168 B staged W1
    __shared__ __align__(16) _Float16 qsh[256];         // q broadcast, f16
    __shared__ __align__(16) _Float16 ush[256];         // u broadcast, f16
    __shared__ __align__(16) float    gsh[256];         // g bounce (wave-local)

    const int t = threadIdx.x;
    const int w = t >> 6;          // wave id: owns components [64w, 64w+64)
    const int l = t & 63;
    const int quad = l >> 4;
    const int s = l & 15;
    const int blk = blockIdx.x;

    // ---- stage W1 -> LDS f16 (padded rows), coalesced ----
    #pragma unroll 1
    for (int k = t; k < 65536 / 4; k += 256) {
        const int row = k >> 6, col4 = (k & 63) * 4;
        float4 v = ((const float4*)W1)[k];
        v4h h; h[0] = (_Float16)v.x; h[1] = (_Float16)v.y;
               h[2] = (_Float16)v.z; h[3] = (_Float16)v.w;
        *(v4h*)(wlds + row * WS + col4) = h;
    }
    __syncthreads();

    // ---- weight frags (both orientations), FULL unroll ----
    // wA[tt][kk] (B-operand, fwd): elem j = W[32kk+8quad+j][16(4w+tt)+s]
    // wB[tt][kk] (A-operand, bwd): elem j = W[16(4w+tt)+s][32kk+8quad+j]
    v8h wA[4][8], wB[4][8];
    #pragma unroll
    for (int tt = 0; tt < 4; ++tt)
        #pragma unroll
        for (int kk = 0; kk < 8; ++kk) {
            wB[tt][kk] = *(const v8h*)(wlds + (16 * (4 * w + tt) + s) * WS
                                            + 32 * kk + 8 * quad);
            #pragma unroll
            for (int j = 0; j < 8; ++j)
                wA[tt][kk][j] =
                    wlds[(32 * kk + 8 * quad + j) * WS + 16 * (4 * w + tt) + s];
        }

    const float b1r = b1[t];
    const float w2r = W2[t];

    float2 qp = ((const float2*)(x0 + (size_t)blk * 512))[t];
    float q0 = qp.x, p0 = qp.y;
    qsh[t] = (_Float16)q0;
    __syncthreads();

    const float dt = 0.01f;
    float accq = 0.f, accp = 0.f, qs = q0, ps = p0;

    #pragma unroll 1
    for (int it = 0; it < NSTEPS * 4; ++it) {
        const int stg = it & 3;

        // ---- forward: z = W^T q.  A = q-replicated, B = wA ----
        v4f Cz0 = {0,0,0,0}, Cz1 = {0,0,0,0}, Cz2 = {0,0,0,0}, Cz3 = {0,0,0,0};
        #pragma unroll
        for (int kk = 0; kk < 8; ++kk) {
            v8h aq = *(const v8h*)(qsh + 32 * kk + 8 * quad);  // bcast read
            Cz0 = __builtin_amdgcn_mfma_f32_16x16x32_f16(aq, wA[0][kk], Cz0, 0, 0, 0);
            Cz1 = __builtin_amdgcn_mfma_f32_16x16x32_f16(aq, wA[1][kk], Cz1, 0, 0, 0);
            Cz2 = __builtin_amdgcn_mfma_f32_16x16x32_f16(aq, wA[2][kk], Cz2, 0, 0, 0);
            Cz3 = __builtin_amdgcn_mfma_f32_16x16x32_f16(aq, wA[3][kk], Cz3, 0, 0, 0);
        }
        // D[.][col=s] = z[16(4w+tt)+s]; lane's component 64w+16quad+s -> tt==quad
        float z = ((quad == 0) ? Cz0[0] : (quad == 1) ? Cz1[0]
                 : (quad == 2) ? Cz2[0] : Cz3[0]) + b1r;

        // ---- nonlinearity (thread t owns hidden unit t) ----
        float e = __expf(2.f * z);            // tanh via exp; saturates ok
        float hh = 1.f - 2.f / (e + 1.f);
        float u = (1.f - hh * hh) * w2r;
        ush[t] = (_Float16)u;
        __syncthreads();

        // ---- backward: g = W u.  A = wB, B = u-replicated ----
        v4f Cg0 = {0,0,0,0}, Cg1 = {0,0,0,0}, Cg2 = {0,0,0,0}, Cg3 = {0,0,0,0};
        #pragma unroll
        for (int kk = 0; kk < 8; ++kk) {
            v8h bu = *(const v8h*)(ush + 32 * kk + 8 * quad);  // bcast read
            Cg0 = __builtin_amdgcn_mfma_f32_16x16x32_f16(wB[0][kk], bu, Cg0, 0, 0, 0);
            Cg1 = __builtin_amdgcn_mfma_f32_16x16x32_f16(wB[1][kk], bu, Cg1, 0, 0, 0);
            Cg2 = __builtin_amdgcn_mfma_f32_16x16x32_f16(wB[2][kk], bu, Cg2, 0, 0, 0);
            Cg3 = __builtin_amdgcn_mfma_f32_16x16x32_f16(wB[3][kk], bu, Cg3, 0, 0, 0);
        }
        // D[row=4quad+r][.] = g[16(4w+tt)+4quad+r]; bounce via wave-local LDS
        if (s == 0) {
            *(v4f*)(gsh + 16 * (4 * w + 0) + 4 * quad) = Cg0;
            *(v4f*)(gsh + 16 * (4 * w + 1) + 4 * quad) = Cg1;
            *(v4f*)(gsh + 16 * (4 * w + 2) + 4 * quad) = Cg2;
            *(v4f*)(gsh + 16 * (4 * w + 3) + 4 * quad) = Cg3;
        }
        // wave w wrote gsh[64w..64w+64) and reads only gsh[t] there:
        // same-wave DS ops are in-order; no barrier needed.
        float g = gsh[t];

        // ---- RK4 bookkeeping for component t ----
        float kq = ps, kp = -g;
        float wgt = (stg == 0 || stg == 3) ? 1.f : 2.f;
        accq += wgt * kq;
        accp += wgt * kp;
        float qn;
        if (stg < 3) {
            float a = (stg == 2) ? dt : 0.5f * dt;
            qs = q0 + a * kq;
            ps = p0 + a * kp;
            qn = qs;
        } else {
            q0 += (dt / 6.f) * accq;
            p0 += (dt / 6.f) * accp;
            accq = 0.f; accp = 0.f;
            qs = q0; ps = p0;
            qn = q0;
        }
        qsh[t] = (_Float16)qn;
        __syncthreads();
    }

    ((float2*)(out + (size_t)blk * 512))[t] = make_float2(q0, p0);
}

extern "C" void kernel_launch(void* const* d_in, const int* in_sizes, int n_in,
                              void* d_out, int out_size, void* d_ws, size_t ws_size,
                              hipStream_t stream) {
    const float* x0 = (const float*)d_in[0];
    const float* W1 = (const float*)d_in[1];
    const float* b1 = (const float*)d_in[2];
    const float* W2 = (const float*)d_in[3];
    // d_in[4] = b2: constant offset, no effect on the gradient/dynamics.
    float* out = (float*)d_out;
    hipLaunchKernelGGL(ham_kernel, dim3(256), dim3(256), 0, stream,
                       x0, W1, b1, W2, out);
}

// Round 8
// 456.840 us; speedup vs baseline: 28.5151x; 1.2141x over previous
//
#include <hip/hip_runtime.h>
#include <stdint.h>

// HamiltonianFlow: x [256, 8, 32, 2] (q,p); H = 0.5*sum(p^2) + MLP(q).
// dq/dt = p, dp/dt = -W1 @ [(1-tanh(z)^2) * W2], z = q^T W1 + b1.
// 100 RK4 steps = 400 strictly sequential fwd+bwd 256x256 matvecs.
//
// R8: R7 measured 3324 cyc/eval vs the 1242-cyc MFMA-pipe floor (MfmaUtil
// 32%, 1 wave/SIMD -> latency exposed). The 256-MFMA/eval cost is invariant
// to how many B-columns carry real data, so: pack TWO trajectories into the
// 16 columns (cols 0-7 traj0, 8-15 traj1) -> per-traj pipe cost halves; and
// run 8 waves (2/SIMD) so wave pairs overlap each other's stalls.
//
// mfma_f32_16x16x32_f16: A[m=lane&15][k=quad*8+j]; B[k=quad*8+j][n=lane&15];
// D[row=quad*4+r][col=lane&15].
// fwd : A = W^T frags (wA: elem j = W[32kk+8q+j][16T+s] -- identical gather
//       to R7), B[k][n] = q_{traj(n)}[32kk+k] -> D = z_{traj(s)}[16T+4q+r].
// bwd : A = W frags (wB, contiguous), B = u-packed -> D = g_{traj(s)}[...].
// Both z and g ROW-owned -> no gsh bounce. Wave w owns tiles {2w,2w+1};
// lane (q,s): traj=s>>3, tile=(s>>2)&1, row r=s&3 -> exactly ONE
// (component,trajectory) per lane: 1 tanh, 1 RK4 update, 1 ds_write each.
// 2 barriers/eval. Weights in regs: 128/wave (fits 2 waves/SIMD budget 256).
// FULL unroll on every reg-array access (R4: dynamic index => scratch).
// Numerics: f16 storage, fp32 MFMA accumulate (R3/R5/R7 class, 1.95e-3).

typedef _Float16 v8h __attribute__((ext_vector_type(8)));
typedef _Float16 v4h __attribute__((ext_vector_type(4)));
typedef float v4f __attribute__((ext_vector_type(4)));

#define NSTEPS 100
#define WS 264   // padded f16 row stride for staging (16B-aligned rows)

__global__ __launch_bounds__(512, 2)
void ham_kernel(const float* __restrict__ x0, const float* __restrict__ W1,
                const float* __restrict__ b1, const float* __restrict__ W2,
                float* __restrict__ out)
{
    __shared__ __align__(16) _Float16 wlds[256 * WS];   // 135168 B staged W1
    __shared__ __align__(16) _Float16 qsh[2][256];      // q, per trajectory
    __shared__ __align__(16) _Float16 ush[2][256];      // u, per trajectory

    const int t = threadIdx.x;
    const int w = t >> 6;            // wave 0..7: owns tiles {2w, 2w+1}
    const int l = t & 63;
    const int quad = l >> 4;
    const int s = l & 15;
    const int traj = s >> 3;         // column group -> trajectory
    const int tt_sel = (s >> 2) & 1; // owned tile within {2w, 2w+1}
    const int r_sel = s & 3;         // owned row within quad block
    const int comp = 16 * (2 * w + tt_sel) + 4 * quad + r_sel;  // owned comp
    const int blk = blockIdx.x;

    // ---- stage W1 -> LDS f16 (padded rows), coalesced ----
    #pragma unroll 1
    for (int k = t; k < 65536 / 4; k += 512) {
        const int row = k >> 6, col4 = (k & 63) * 4;
        float4 v = ((const float4*)W1)[k];
        v4h h; h[0] = (_Float16)v.x; h[1] = (_Float16)v.y;
               h[2] = (_Float16)v.z; h[3] = (_Float16)v.w;
        *(v4h*)(wlds + row * WS + col4) = h;
    }
    __syncthreads();

    // ---- weight frags, both orientations, FULL unroll ----
    // wA[tt][kk] (A-op, fwd = W^T): elem j = W[32kk+8quad+j][16(2w+tt)+s]
    // wB[tt][kk] (A-op, bwd = W)  : elem j = W[16(2w+tt)+s][32kk+8quad+j]
    v8h wA[2][8], wB[2][8];
    #pragma unroll
    for (int tt = 0; tt < 2; ++tt)
        #pragma unroll
        for (int kk = 0; kk < 8; ++kk) {
            wB[tt][kk] = *(const v8h*)(wlds + (16 * (2 * w + tt) + s) * WS
                                            + 32 * kk + 8 * quad);
            #pragma unroll
            for (int j = 0; j < 8; ++j)
                wA[tt][kk][j] =
                    wlds[(32 * kk + 8 * quad + j) * WS + 16 * (2 * w + tt) + s];
        }

    const float b1r = b1[comp];
    const float w2r = W2[comp];

    // ---- state: one (comp, traj) per lane ----
    const int gtraj = 2 * blk + traj;
    float2 qp = ((const float2*)(x0 + (size_t)gtraj * 512))[comp];
    float q0 = qp.x, p0 = qp.y;
    qsh[traj][comp] = (_Float16)q0;
    __syncthreads();

    const float dt = 0.01f;
    float accq = 0.f, accp = 0.f, qs = q0, ps = p0;

    #pragma unroll 1
    for (int it = 0; it < NSTEPS * 4; ++it) {
        const int stg = it & 3;

        // ---- forward: z = W^T q (per traj). A = wA, B = q-packed ----
        v4f Cz00 = {0,0,0,0}, Cz01 = {0,0,0,0};   // tile 0, K-halves
        v4f Cz10 = {0,0,0,0}, Cz11 = {0,0,0,0};   // tile 1, K-halves
        #pragma unroll
        for (int kk = 0; kk < 4; ++kk) {
            v8h bq = *(const v8h*)(&qsh[traj][0] + 32 * kk + 8 * quad);
            Cz00 = __builtin_amdgcn_mfma_f32_16x16x32_f16(wA[0][kk], bq, Cz00, 0, 0, 0);
            Cz10 = __builtin_amdgcn_mfma_f32_16x16x32_f16(wA[1][kk], bq, Cz10, 0, 0, 0);
        }
        #pragma unroll
        for (int kk = 4; kk < 8; ++kk) {
            v8h bq = *(const v8h*)(&qsh[traj][0] + 32 * kk + 8 * quad);
            Cz01 = __builtin_amdgcn_mfma_f32_16x16x32_f16(wA[0][kk], bq, Cz01, 0, 0, 0);
            Cz11 = __builtin_amdgcn_mfma_f32_16x16x32_f16(wA[1][kk], bq, Cz11, 0, 0, 0);
        }
        v4f Cz0 = Cz00 + Cz01, Cz1 = Cz10 + Cz11;

        // ---- pick own z: D[row=4q+r][col=s] = z_traj(s)[16T+4q+r] ----
        v4f zt = tt_sel ? Cz1 : Cz0;
        float zv = (r_sel & 2) ? ((r_sel & 1) ? zt[3] : zt[2])
                               : ((r_sel & 1) ? zt[1] : zt[0]);
        float z = zv + b1r;
        float e = __expf(2.f * z);            // tanh via exp; saturates ok
        float hh = 1.f - 2.f / (e + 1.f);
        float u = (1.f - hh * hh) * w2r;
        ush[traj][comp] = (_Float16)u;
        __syncthreads();

        // ---- backward: g = W u (per traj). A = wB, B = u-packed ----
        v4f Cg00 = {0,0,0,0}, Cg01 = {0,0,0,0};
        v4f Cg10 = {0,0,0,0}, Cg11 = {0,0,0,0};
        #pragma unroll
        for (int kk = 0; kk < 4; ++kk) {
            v8h bu = *(const v8h*)(&ush[traj][0] + 32 * kk + 8 * quad);
            Cg00 = __builtin_amdgcn_mfma_f32_16x16x32_f16(wB[0][kk], bu, Cg00, 0, 0, 0);
            Cg10 = __builtin_amdgcn_mfma_f32_16x16x32_f16(wB[1][kk], bu, Cg10, 0, 0, 0);
        }
        #pragma unroll
        for (int kk = 4; kk < 8; ++kk) {
            v4f dummy;
            v8h bu = *(const v8h*)(&ush[traj][0] + 32 * kk + 8 * quad);
            Cg01 = __builtin_amdgcn_mfma_f32_16x16x32_f16(wB[0][kk], bu, Cg01, 0, 0, 0);
            Cg11 = __builtin_amdgcn_mfma_f32_16x16x32_f16(wB[1][kk], bu, Cg11, 0, 0, 0);
            (void)dummy;
        }
        v4f Cg0 = Cg00 + Cg01, Cg1 = Cg10 + Cg11;

        v4f gt = tt_sel ? Cg1 : Cg0;
        float g = (r_sel & 2) ? ((r_sel & 1) ? gt[3] : gt[2])
                              : ((r_sel & 1) ? gt[1] : gt[0]);

        // ---- RK4 bookkeeping for (comp, traj) ----
        float kq = ps, kp = -g;
        float wgt = (stg == 0 || stg == 3) ? 1.f : 2.f;
        accq += wgt * kq;
        accp += wgt * kp;
        float qn;
        if (stg < 3) {
            float a = (stg == 2) ? dt : 0.5f * dt;
            qs = q0 + a * kq;
            ps = p0 + a * kp;
            qn = qs;
        } else {
            q0 += (dt / 6.f) * accq;
            p0 += (dt / 6.f) * accp;
            accq = 0.f; accp = 0.f;
            qs = q0; ps = p0;
            qn = q0;
        }
        qsh[traj][comp] = (_Float16)qn;
        __syncthreads();
    }

    ((float2*)(out + (size_t)gtraj * 512))[comp] = make_float2(q0, p0);
}

extern "C" void kernel_launch(void* const* d_in, const int* in_sizes, int n_in,
                              void* d_out, int out_size, void* d_ws, size_t ws_size,
                              hipStream_t stream) {
    const float* x0 = (const float*)d_in[0];
    const float* W1 = (const float*)d_in[1];
    const float* b1 = (const float*)d_in[2];
    const float* W2 = (const float*)d_in[3];
    // d_in[4] = b2: constant offset, no effect on the gradient/dynamics.
    float* out = (float*)d_out;
    // 128 blocks x 2 packed trajectories = 256 trajectories
    hipLaunchKernelGGL(ham_kernel, dim3(128), dim3(512), 0, stream,
                       x0, W1, b1, W2, out);
}